// Round 3
// baseline (355.414 us; speedup 1.0000x reference)
//
#include <hip/hip_runtime.h>
#include <cstdint>

typedef __bf16 bf16;
typedef __bf16 bf16x8 __attribute__((ext_vector_type(8)));
typedef __bf16 bf16x4 __attribute__((ext_vector_type(4)));
typedef float  f32x4  __attribute__((ext_vector_type(4)));

#define HIDDEN 2304
#define NQ 2048
#define NKV 1024
#define SEQ 2048

typedef __attribute__((address_space(1))) void gv_t;
typedef __attribute__((address_space(3))) void lv_t;
__device__ __forceinline__ void gld16(const void* g, void* l) {
  __builtin_amdgcn_global_load_lds((gv_t*)g, (lv_t*)l, 16, 0, 0);
}

// ---------------- RMSNorm + bf16 cast ----------------
__global__ __launch_bounds__(256) void rmsnorm_kernel(const float* __restrict__ x,
                                                      const float* __restrict__ w,
                                                      bf16* __restrict__ xb) {
  const int row = blockIdx.x, t = threadIdx.x;
  const float* xr = x + (size_t)row * HIDDEN;
  float v[9]; float ss = 0.f;
#pragma unroll
  for (int i = 0; i < 9; ++i) { v[i] = xr[t + i * 256]; ss += v[i] * v[i]; }
#pragma unroll
  for (int o = 32; o; o >>= 1) ss += __shfl_xor(ss, o, 64);
  __shared__ float wss[4];
  if ((t & 63) == 0) wss[t >> 6] = ss;
  __syncthreads();
  ss = wss[0] + wss[1] + wss[2] + wss[3];
  const float rs = rsqrtf(ss * (1.0f / HIDDEN) + 1e-6f);
  bf16* xo = xb + (size_t)row * HIDDEN;
#pragma unroll
  for (int i = 0; i < 9; ++i) xo[t + i * 256] = (bf16)(v[i] * rs * (1.0f + w[t + i * 256]));
}

// ---------------- fused f32 -> bf16 weight convert (Wq,Wk,Wv,Wo) ----------
#define NW0 (2048 * 2304)
#define NW1 (1024 * 2304)
#define NW3 (2304 * 2048)
__global__ __launch_bounds__(256) void cvt4_kernel(const float* __restrict__ s0, const float* __restrict__ s1,
                                                   const float* __restrict__ s2, const float* __restrict__ s3,
                                                   bf16* __restrict__ d0, bf16* __restrict__ d1,
                                                   bf16* __restrict__ d2, bf16* __restrict__ d3) {
  int i = (blockIdx.x * 256 + threadIdx.x) * 4;
  const float* s; bf16* d;
  if (i < NW0) { s = s0; d = d0; }
  else if (i < NW0 + NW1) { s = s1; d = d1; i -= NW0; }
  else if (i < NW0 + 2 * NW1) { s = s2; d = d2; i -= NW0 + NW1; }
  else { s = s3; d = d3; i -= NW0 + 2 * NW1; }
  const float4 f = *(const float4*)(s + i);
  bf16x4 o; o.x = (bf16)f.x; o.y = (bf16)f.y; o.z = (bf16)f.z; o.w = (bf16)f.w;
  *(bf16x4*)(d + i) = o;
}

// ---------------- RoPE in-place on q and k (bf16) ----------------
__global__ __launch_bounds__(256) void rope_kernel(bf16* __restrict__ q, bf16* __restrict__ k,
                                                   const float* __restrict__ cosb,
                                                   const float* __restrict__ sinb) {
  const int tid = blockIdx.x * 256 + threadIdx.x;
  const int QN = 4096 * 8 * 128;
  const int KN = 4096 * 4 * 128;
  bf16* p; int row, d;
  if (tid < QN) {
    row = tid >> 10; const int rem = tid & 1023; d = rem & 127;
    p = q + (size_t)row * NQ + (rem >> 7) * 256 + d;
  } else {
    const int t2 = tid - QN; if (t2 >= KN) return;
    row = t2 >> 9; const int rem = t2 & 511; d = rem & 127;
    p = k + (size_t)row * NKV + (rem >> 7) * 256 + d;
  }
  const size_t cb = (size_t)row * 256 + d;
  const float c0 = cosb[cb], s0 = sinb[cb], c1 = cosb[cb + 128], s1 = sinb[cb + 128];
  const float a = (float)p[0], b = (float)p[128];
  p[0]   = (bf16)(a * c0 - b * s0);
  p[128] = (bf16)(b * c1 + a * s1);
}

// ---------------- bf16 GEMM (m97 structure), C = A[M,K] * B[N,K]^T ----------
// MODE 0: fused QKV epilogue. N=4096: n<2048 -> Q row-major (ld 2048);
//         n in [2048,3072) -> K row-major (ld 1024); n >= 3072 -> V^T
//         [B][1024][SEQ]. Region boundaries are 128-aligned => wave-uniform.
// MODE 1: split-K (blockIdx.z selects 1024-wide K slice), f32 atomicAdd into
//         fo (pre-initialized with residual). Exactly 2 adds per element.
template<int MODE>
__global__ __launch_bounds__(256) void gemm_bt(const bf16* __restrict__ A, const bf16* __restrict__ B,
                                               bf16* __restrict__ Cq, bf16* __restrict__ Ck,
                                               bf16* __restrict__ Cvt, float* __restrict__ fo,
                                               int M, int N, int K) {
  __shared__ bf16 As[128 * 64];
  __shared__ bf16 Bs[128 * 64];
  const int t = threadIdx.x, lane = t & 63, w = t >> 6;
  const int wr = w >> 1, wc = w & 1;
  const int r16 = lane & 15, g = lane >> 4;
  const int m0 = blockIdx.x * 128, n0 = blockIdx.y * 128;
  int kbeg = 0, kend = K;
  if constexpr (MODE == 1) { kbeg = blockIdx.z * 1024; kend = kbeg + 1024; }
  f32x4 acc[4][4] = {};
  for (int k0 = kbeg; k0 < kend; k0 += 64) {
    __syncthreads();
#pragma unroll
    for (int c = 0; c < 4; ++c) {
      const int o = c * 4096 + w * 1024 + lane * 16;   // byte offset in 16KB tile
      const int row = o >> 7, col = (o & 127) >> 1;    // row, bf16 col
      gld16(&A[(size_t)(m0 + row) * K + k0 + col], (char*)As + o);
      gld16(&B[(size_t)(n0 + row) * K + k0 + col], (char*)Bs + o);
    }
    __syncthreads();
#pragma unroll
    for (int ks = 0; ks < 2; ++ks) {
      bf16x8 af[4], bfv[4];
#pragma unroll
      for (int i = 0; i < 4; ++i) {
        af[i]  = *(const bf16x8*)&As[(wr * 64 + i * 16 + r16) * 64 + ks * 32 + g * 8];
        bfv[i] = *(const bf16x8*)&Bs[(wc * 64 + i * 16 + r16) * 64 + ks * 32 + g * 8];
      }
#pragma unroll
      for (int i = 0; i < 4; ++i)
#pragma unroll
        for (int j = 0; j < 4; ++j)
          acc[i][j] = __builtin_amdgcn_mfma_f32_16x16x32_bf16(af[i], bfv[j], acc[i][j], 0, 0, 0);
    }
  }
#pragma unroll
  for (int i = 0; i < 4; ++i)
#pragma unroll
    for (int j = 0; j < 4; ++j) {
      const int mb = m0 + wr * 64 + i * 16 + g * 4;
      const int n = n0 + wc * 64 + j * 16 + r16;
#pragma unroll
      for (int e = 0; e < 4; ++e) {
        const int m = mb + e;
        const float vv = acc[i][j][e];
        if constexpr (MODE == 0) {
          if (n0 < 2048) {
            Cq[(size_t)m * 2048 + n] = (bf16)vv;
          } else if (n0 < 3072) {
            Ck[(size_t)m * 1024 + (n - 2048)] = (bf16)vv;
          } else {
            const int bb = m >> 11, s = m & 2047, col = n - 3072;
            Cvt[((size_t)bb * 1024 + col) * SEQ + s] = (bf16)vv;
          }
        } else {
          atomicAdd(&fo[(size_t)m * N + n], vv);
        }
      }
    }
}

// ---------------- attention tile loads (K 32x256, V^T 256x32) ----------------
__device__ __forceinline__ void attn_load(const bf16* __restrict__ kgp, const bf16* __restrict__ vgp,
                                          int j0, int t, bf16x8* kr, bf16x8* vr) {
#pragma unroll
  for (int it = 0; it < 4; ++it) {
    const int flat = it * 2048 + t * 8;
    kr[it] = *(const bf16x8*)&kgp[(size_t)((flat >> 8) + j0) * NKV + (flat & 255)];
    vr[it] = *(const bf16x8*)&vgp[(size_t)(flat >> 5) * SEQ + j0 + (flat & 31)];
  }
}

// ---------------- Flash attention: QT=64 (4 waves x 16 rows), KT=32 --------
// No online max: softcap bounds scores to [-50,50] and the (always-allowed)
// diagonal has score >= 0, so fixed shift M=50 is safe: p = exp(v-50) with
// p_diag >= e^-50 (normal). p = exp(-100/(e^{2y}+1)), y = s*SCALING/SOFTCAP.
__global__ __launch_bounds__(256) void attn_kernel(const bf16* __restrict__ q, const bf16* __restrict__ k,
                                                   const bf16* __restrict__ vt, bf16* __restrict__ ao) {
  __shared__ bf16 smem[21248];
  bf16* const qs  = smem;          // [64][264] (phase 1 only)
  bf16* const ksl = smem;          // [32][264]
  bf16* const vtl = smem + 8448;   // [256][40]
  bf16* const pl  = smem + 18688;  // [4][16][40]
  int qt = blockIdx.x;
  const int h = blockIdx.y, b = blockIdx.z;
  if (b) qt = 31 - qt;             // pair heavy+light q-tiles across the grid
  const int kvh = h >> 1;
  const int t = threadIdx.x, lane = t & 63, w = t >> 6;
  const int r16 = lane & 15, g = lane >> 4;
  const int i_base = qt * 64;

  {  // stage Q tile 64x256
    const bf16* qg = q + ((size_t)(b * SEQ + i_base)) * NQ + h * 256;
#pragma unroll
    for (int it = 0; it < 8; ++it) {
      const int flat = it * 2048 + t * 8;
      const int row = flat >> 8, dd = flat & 255;
      *(bf16x8*)&qs[row * 264 + dd] = *(const bf16x8*)&qg[(size_t)row * NQ + dd];
    }
  }
  __syncthreads();
  bf16x8 aq[8];
#pragma unroll
  for (int c = 0; c < 8; ++c) aq[c] = *(const bf16x8*)&qs[(w * 16 + r16) * 264 + c * 32 + g * 8];

  f32x4 oacc[16] = {};
  float lrun[4] = {0.f, 0.f, 0.f, 0.f};
  int jb = i_base - 1023; if (jb < 0) jb = 0; jb &= ~31;
  const int je = i_base + 63;
  const bf16* kg = k + (size_t)b * SEQ * NKV + kvh * 256;
  const bf16* vg = vt + ((size_t)b * NKV + kvh * 256) * SEQ;

  bf16x8 kr[4], vr[4];
  attn_load(kg, vg, jb, t, kr, vr);

  for (int j0 = jb; j0 <= je; j0 += 32) {
    __syncthreads();
#pragma unroll
    for (int it = 0; it < 4; ++it) {  // regs -> LDS
      const int flat = it * 2048 + t * 8;
      *(bf16x8*)&ksl[(flat >> 8) * 264 + (flat & 255)] = kr[it];
      *(bf16x8*)&vtl[(flat >> 5) * 40 + (flat & 31)] = vr[it];
    }
    __syncthreads();
    const int jn = (j0 + 32 <= je) ? (j0 + 32) : j0;
    attn_load(kg, vg, jn, t, kr, vr);  // prefetch next tile (hides under compute)

    f32x4 sc0 = {}, sc1 = {};
#pragma unroll
    for (int c = 0; c < 8; ++c) {
      const bf16x8 b0 = *(const bf16x8*)&ksl[r16 * 264 + c * 32 + g * 8];
      const bf16x8 b1 = *(const bf16x8*)&ksl[(16 + r16) * 264 + c * 32 + g * 8];
      sc0 = __builtin_amdgcn_mfma_f32_16x16x32_bf16(aq[c], b0, sc0, 0, 0, 0);
      sc1 = __builtin_amdgcn_mfma_f32_16x16x32_bf16(aq[c], b1, sc1, 0, 0, 0);
    }
    const bool full = (j0 + 31 <= i_base) && (i_base + 63 - j0 < 1024);
#pragma unroll
    for (int e = 0; e < 4; ++e) {
      const float t0 = __expf(sc0[e] * 0.0025f);
      const float t1 = __expf(sc1[e] * 0.0025f);
      float p0 = __expf(-100.0f / (t0 + 1.0f));
      float p1 = __expf(-100.0f / (t1 + 1.0f));
      if (!full) {
        const int irow = i_base + w * 16 + g * 4 + e;
        const int jg0 = j0 + r16, jg1 = j0 + 16 + r16;
        if (jg0 > irow || irow - jg0 >= 1024) p0 = 0.f;
        if (jg1 > irow || irow - jg1 >= 1024) p1 = 0.f;
      }
      const bf16 b0 = (bf16)p0, b1 = (bf16)p1;
      lrun[e] += (float)b0 + (float)b1;
      pl[w * 640 + (g * 4 + e) * 40 + r16] = b0;
      pl[w * 640 + (g * 4 + e) * 40 + 16 + r16] = b1;
    }
    // per-wave P buffer: same-wave LDS write->read dependency, no barrier needed
    const bf16x8 pa = *(const bf16x8*)&pl[w * 640 + r16 * 40 + g * 8];
#pragma unroll
    for (int nf = 0; nf < 16; ++nf) {
      const bf16x8 vb = *(const bf16x8*)&vtl[(nf * 16 + r16) * 40 + g * 8];
      oacc[nf] = __builtin_amdgcn_mfma_f32_16x16x32_bf16(pa, vb, oacc[nf], 0, 0, 0);
    }
  }
  float inv[4];
#pragma unroll
  for (int e = 0; e < 4; ++e) {
#pragma unroll
    for (int o = 1; o < 16; o <<= 1) lrun[e] += __shfl_xor(lrun[e], o, 64);
    inv[e] = 1.0f / lrun[e];
  }
  bf16* aor = ao + ((size_t)(b * SEQ + i_base + w * 16)) * NQ + h * 256;
#pragma unroll
  for (int nf = 0; nf < 16; ++nf)
#pragma unroll
    for (int e = 0; e < 4; ++e)
      aor[(size_t)(g * 4 + e) * NQ + nf * 16 + r16] = (bf16)(oacc[nf][e] * inv[e]);
}

extern "C" void kernel_launch(void* const* d_in, const int* in_sizes, int n_in,
                              void* d_out, int out_size, void* d_ws, size_t ws_size,
                              hipStream_t stream) {
  const float* hs   = (const float*)d_in[0];
  const float* cosb = (const float*)d_in[1];
  const float* sinb = (const float*)d_in[2];
  const float* rw   = (const float*)d_in[3];
  const float* Wq   = (const float*)d_in[4];
  const float* Wk   = (const float*)d_in[5];
  const float* Wv   = (const float*)d_in[6];
  const float* Wo   = (const float*)d_in[7];
  float* out = (float*)d_out;
  char* ws = (char*)d_ws;

  bf16* xb   = (bf16*)(ws);             // 4096x2304
  bf16* wqkv = (bf16*)(ws + 18874368);  // [4096][2304]: Wq(2048) | Wk(1024) | Wv(1024)
  bf16* wkb  = wqkv + (size_t)2048 * 2304;
  bf16* wvb  = wqkv + (size_t)3072 * 2304;
  bf16* wob  = (bf16*)(ws + 37748736);  // 2304x2048
  bf16* qg   = (bf16*)(ws + 47185920);  // 4096x2048
  bf16* kg   = (bf16*)(ws + 63963136);  // 4096x1024
  bf16* vtg  = (bf16*)(ws + 72351744);  // [2][1024][2048]
  bf16* ag   = (bf16*)(ws + 80740352);  // 4096x2048

  rmsnorm_kernel<<<4096, 256, 0, stream>>>(hs, rw, xb);
  cvt4_kernel<<<(NW0 + 2 * NW1 + NW3) / 4 / 256, 256, 0, stream>>>(Wq, Wk, Wv, Wo, wqkv, wkb, wvb, wob);
  gemm_bt<0><<<dim3(32, 32), 256, 0, stream>>>(xb, wqkv, qg, kg, vtg, nullptr, 4096, 4096, 2304);
  rope_kernel<<<(4096 * 8 * 128 + 4096 * 4 * 128) / 256, 256, 0, stream>>>(qg, kg, cosb, sinb);
  attn_kernel<<<dim3(32, 8, 2), 256, 0, stream>>>(qg, kg, vtg, ag);
  hipMemcpyAsync(out, hs, (size_t)4096 * 2304 * sizeof(float), hipMemcpyDeviceToDevice, stream);
  gemm_bt<1><<<dim3(32, 18, 2), 256, 0, stream>>>(ag, wob, nullptr, nullptr, nullptr, out, 4096, 2304, 2048);
}

// Round 4
// 267.671 us; speedup vs baseline: 1.3278x; 1.3278x over previous
//
#include <hip/hip_runtime.h>
#include <cstdint>

typedef __bf16 bf16;
typedef __bf16 bf16x8 __attribute__((ext_vector_type(8)));
typedef __bf16 bf16x4 __attribute__((ext_vector_type(4)));
typedef float  f32x4  __attribute__((ext_vector_type(4)));

#define HIDDEN 2304
#define NQ 2048
#define NKV 1024
#define SEQ 2048

typedef __attribute__((address_space(1))) void gv_t;
typedef __attribute__((address_space(3))) void lv_t;
__device__ __forceinline__ void gld16(const void* g, void* l) {
  __builtin_amdgcn_global_load_lds((gv_t*)g, (lv_t*)l, 16, 0, 0);
}

#define BAR()   asm volatile("s_barrier" ::: "memory")
#define LGKM0() asm volatile("s_waitcnt lgkmcnt(0)" ::: "memory")
#define VM6()   asm volatile("s_waitcnt vmcnt(6)" ::: "memory")
#define VM0()   asm volatile("s_waitcnt vmcnt(0)" ::: "memory")

// ---------------- RMSNorm + bf16 cast ----------------
__global__ __launch_bounds__(256) void rmsnorm_kernel(const float* __restrict__ x,
                                                      const float* __restrict__ w,
                                                      bf16* __restrict__ xb) {
  const int row = blockIdx.x, t = threadIdx.x;
  const float* xr = x + (size_t)row * HIDDEN;
  float v[9]; float ss = 0.f;
#pragma unroll
  for (int i = 0; i < 9; ++i) { v[i] = xr[t + i * 256]; ss += v[i] * v[i]; }
#pragma unroll
  for (int o = 32; o; o >>= 1) ss += __shfl_xor(ss, o, 64);
  __shared__ float wss[4];
  if ((t & 63) == 0) wss[t >> 6] = ss;
  __syncthreads();
  ss = wss[0] + wss[1] + wss[2] + wss[3];
  const float rs = rsqrtf(ss * (1.0f / HIDDEN) + 1e-6f);
  bf16* xo = xb + (size_t)row * HIDDEN;
#pragma unroll
  for (int i = 0; i < 9; ++i) xo[t + i * 256] = (bf16)(v[i] * rs * (1.0f + w[t + i * 256]));
}

// ---------------- fused f32 -> bf16 weight convert (Wq,Wk,Wv,Wo) ----------
#define NW0 (2048 * 2304)
#define NW1 (1024 * 2304)
#define NW3 (2304 * 2048)
__global__ __launch_bounds__(256) void cvt4_kernel(const float* __restrict__ s0, const float* __restrict__ s1,
                                                   const float* __restrict__ s2, const float* __restrict__ s3,
                                                   bf16* __restrict__ d0, bf16* __restrict__ d1,
                                                   bf16* __restrict__ d2, bf16* __restrict__ d3) {
  int i = (blockIdx.x * 256 + threadIdx.x) * 4;
  const float* s; bf16* d;
  if (i < NW0) { s = s0; d = d0; }
  else if (i < NW0 + NW1) { s = s1; d = d1; i -= NW0; }
  else if (i < NW0 + 2 * NW1) { s = s2; d = d2; i -= NW0 + NW1; }
  else { s = s3; d = d3; i -= NW0 + 2 * NW1; }
  const float4 f = *(const float4*)(s + i);
  bf16x4 o; o.x = (bf16)f.x; o.y = (bf16)f.y; o.z = (bf16)f.z; o.w = (bf16)f.w;
  *(bf16x4*)(d + i) = o;
}

// ---------------- RoPE in-place on q and k (bf16) ----------------
__global__ __launch_bounds__(256) void rope_kernel(bf16* __restrict__ q, bf16* __restrict__ k,
                                                   const float* __restrict__ cosb,
                                                   const float* __restrict__ sinb) {
  const int tid = blockIdx.x * 256 + threadIdx.x;
  const int QN = 4096 * 8 * 128;
  const int KN = 4096 * 4 * 128;
  bf16* p; int row, d;
  if (tid < QN) {
    row = tid >> 10; const int rem = tid & 1023; d = rem & 127;
    p = q + (size_t)row * NQ + (rem >> 7) * 256 + d;
  } else {
    const int t2 = tid - QN; if (t2 >= KN) return;
    row = t2 >> 9; const int rem = t2 & 511; d = rem & 127;
    p = k + (size_t)row * NKV + (rem >> 7) * 256 + d;
  }
  const size_t cb = (size_t)row * 256 + d;
  const float c0 = cosb[cb], s0 = sinb[cb], c1 = cosb[cb + 128], s1 = sinb[cb + 128];
  const float a = (float)p[0], b = (float)p[128];
  p[0]   = (bf16)(a * c0 - b * s0);
  p[128] = (bf16)(b * c1 + a * s1);
}

// ======== 256x256 8-phase GEMM (T1+T2+T3+T4+T5), C = A[M,K]*B[N,K]^T ========
// 512 threads = 8 waves (2M x 4N). BK=64. LDS: 2 x 64KB buffers, each
// {A0,A1,B0,B1} halves of 16KB ([128 rows][128 bytes], T2 XOR-swizzled:
// lds[r][c ^ ((r&7)<<4)] holds logical (r,c); stage pre-swizzles the GLOBAL
// source (rule #21), gld16 dest stays linear).
// Per tile t: P1 reads A-mh0+B (16 ds_read_b128), stages (t+1).B1.
//             P2 reads A-mh1 (8), then lgkmcnt(0): ALL tile-t reads confirmed
//               before any same-buffer overwrite.
//             P3 stages (t+2).A0.  P4 stages (t+2).A1,B0 + vmcnt(6) (counted,
//               confirms all 4 halves of t+1; 3 halves stay in flight).
// Each phase: barrier; setprio(1); 16 MFMA; setprio(0); barrier.
__device__ __forceinline__ void stage_half(const char* gbase, int stride, char* ldshalf, int tid) {
  const int c2 = ((tid & 7) * 16) ^ (((tid >> 3) & 7) << 4);  // pre-swizzled global col
#pragma unroll
  for (int q = 0; q < 2; ++q) {
    const int r = q * 64 + (tid >> 3);
    gld16(gbase + (size_t)r * stride + c2, ldshalf + q * 8192 + tid * 16);
  }
}

template<int MH, int NH>
__device__ __forceinline__ void mfma_cluster(const bf16x8 (&af)[4][2], const bf16x8 (&bb)[4][2],
                                             f32x4 (&acc)[8][4]) {
  __builtin_amdgcn_s_setprio(1);
#pragma unroll
  for (int m = 0; m < 4; ++m)
#pragma unroll
    for (int n = 0; n < 2; ++n) {
      f32x4 c = acc[MH * 4 + m][NH * 2 + n];
      c = __builtin_amdgcn_mfma_f32_16x16x32_bf16(af[m][0], bb[NH * 2 + n][0], c, 0, 0, 0);
      c = __builtin_amdgcn_mfma_f32_16x16x32_bf16(af[m][1], bb[NH * 2 + n][1], c, 0, 0, 0);
      acc[MH * 4 + m][NH * 2 + n] = c;
    }
  __builtin_amdgcn_s_setprio(0);
}

// MODE 0: fused QKV epilogue (N=4096: Q | K | V^T regions, 256-aligned).
// MODE 1: f32 out += residual (direct, no atomics).
template<int NT, int NY, int MODE>
__global__ __launch_bounds__(512) void gemm8p(const bf16* __restrict__ A, const bf16* __restrict__ B,
                                              bf16* __restrict__ Cq, bf16* __restrict__ Ck,
                                              bf16* __restrict__ Cvt, float* __restrict__ fo,
                                              const float* __restrict__ resid, int Nd) {
  __shared__ char lds[131072];
  const int Ks = NT * 128;  // row stride in BYTES
  const char* Aby = (const char*)A;
  const char* Bby = (const char*)B;

  int wg = blockIdx.x;
  const int chunk = (int)gridDim.x >> 3;          // grids are multiples of 8
  wg = (wg & 7) * chunk + (wg >> 3);              // XCD-bijective swizzle
  const int by = wg % NY, bx = wg / NY;
  const int m0 = bx * 256, n0 = by * 256;

  const int tid = threadIdx.x, lane = tid & 63, wv = tid >> 6;
  const int wm = wv >> 2, wn = wv & 3;
  const int r16 = lane & 15, g = lane >> 4;
  const int xr = (r16 & 7) << 4;
  const int cb0 = (g * 16) ^ xr, cb1 = (64 + g * 16) ^ xr;
  const int rdA = wm * 16384 + r16 * 128;
  const int rdB = 32768 + (wn >> 1) * 16384 + (wn & 1) * 8192 + r16 * 128;

  f32x4 acc[8][4] = {};

  // ---- prologue: tile0 {A0,A1,B0,B1} -> buf0, tile1 {A0,A1,B0} -> buf1 ----
  stage_half(Aby + (size_t)m0 * Ks,           Ks, lds + 0,     tid);
  stage_half(Aby + (size_t)(m0 + 128) * Ks,   Ks, lds + 16384, tid);
  stage_half(Bby + (size_t)n0 * Ks,           Ks, lds + 32768, tid);
  stage_half(Bby + (size_t)(n0 + 128) * Ks,   Ks, lds + 49152, tid);
  stage_half(Aby + (size_t)m0 * Ks + 128,         Ks, lds + 65536 + 0,     tid);
  stage_half(Aby + (size_t)(m0 + 128) * Ks + 128, Ks, lds + 65536 + 16384, tid);
  stage_half(Bby + (size_t)n0 * Ks + 128,         Ks, lds + 65536 + 32768, tid);
  VM6(); BAR();

  for (int t = 0; t < NT; ++t) {
    const char* bufc = lds + (size_t)(t & 1) * 65536;
    char* bufn = lds + (size_t)((t + 1) & 1) * 65536;
    char* bufs = lds + (size_t)(t & 1) * 65536;  // tile t+2 shares parity with t
    bf16x8 a0[4][2], a1[4][2], bb[4][2];
    // ---- P1: A-mh0 + all B reads; stage (t+1).B1 ----
#pragma unroll
    for (int m = 0; m < 4; ++m) {
      a0[m][0] = *(const bf16x8*)(bufc + rdA + m * 2048 + cb0);
      a0[m][1] = *(const bf16x8*)(bufc + rdA + m * 2048 + cb1);
    }
#pragma unroll
    for (int n = 0; n < 4; ++n) {
      bb[n][0] = *(const bf16x8*)(bufc + rdB + n * 2048 + cb0);
      bb[n][1] = *(const bf16x8*)(bufc + rdB + n * 2048 + cb1);
    }
    if (t + 1 < NT)
      stage_half(Bby + (size_t)(n0 + 128) * Ks + (size_t)(t + 1) * 128, Ks, bufn + 49152, tid);
    BAR();
    mfma_cluster<0, 0>(a0, bb, acc);
    BAR();
    // ---- P2: A-mh1 reads; fence ALL tile-t reads before overwrites ----
#pragma unroll
    for (int m = 0; m < 4; ++m) {
      a1[m][0] = *(const bf16x8*)(bufc + rdA + 8192 + m * 2048 + cb0);
      a1[m][1] = *(const bf16x8*)(bufc + rdA + 8192 + m * 2048 + cb1);
    }
    BAR();
    mfma_cluster<0, 1>(a0, bb, acc);
    LGKM0();
    BAR();
    // ---- P3: stage (t+2).A0 (same buffer as t; safe after P2 fence) ----
    if (t + 2 < NT)
      stage_half(Aby + (size_t)m0 * Ks + (size_t)(t + 2) * 128, Ks, bufs + 0, tid);
    BAR();
    mfma_cluster<1, 0>(a1, bb, acc);
    BAR();
    // ---- P4: stage (t+2).A1,B0; counted vmcnt confirms tile t+1 ----
    if (t + 2 < NT) {
      stage_half(Aby + (size_t)(m0 + 128) * Ks + (size_t)(t + 2) * 128, Ks, bufs + 16384, tid);
      stage_half(Bby + (size_t)n0 * Ks + (size_t)(t + 2) * 128, Ks, bufs + 32768, tid);
    }
    if (t < NT - 2) { VM6(); } else if (t == NT - 2) { VM0(); }
    BAR();
    mfma_cluster<1, 1>(a1, bb, acc);
    BAR();
  }

  // ---- epilogue ----
  const int mrow = m0 + wm * 128 + g * 4;
  const int ncol = n0 + wn * 64 + r16;
#pragma unroll
  for (int i = 0; i < 8; ++i)
#pragma unroll
    for (int j = 0; j < 4; ++j)
#pragma unroll
      for (int e = 0; e < 4; ++e) {
        const int m = mrow + i * 16 + e;
        const int n = ncol + j * 16;
        const float vv = acc[i][j][e];
        if constexpr (MODE == 0) {
          if (n0 < 2048) {
            Cq[(size_t)m * 2048 + n] = (bf16)vv;
          } else if (n0 < 3072) {
            Ck[(size_t)m * 1024 + (n - 2048)] = (bf16)vv;
          } else {
            const int b2 = m >> 11, s = m & 2047;
            Cvt[((size_t)b2 * 1024 + (n - 3072)) * SEQ + s] = (bf16)vv;
          }
        } else {
          fo[(size_t)m * Nd + n] = vv + resid[(size_t)m * Nd + n];
        }
      }
}

// ---------------- attention tile loads (K 32x256, V^T 256x32) ----------------
__device__ __forceinline__ void attn_load(const bf16* __restrict__ kgp, const bf16* __restrict__ vgp,
                                          int j0, int t, bf16x8* kr, bf16x8* vr) {
#pragma unroll
  for (int it = 0; it < 4; ++it) {
    const int flat = it * 2048 + t * 8;
    kr[it] = *(const bf16x8*)&kgp[(size_t)((flat >> 8) + j0) * NKV + (flat & 255)];
    vr[it] = *(const bf16x8*)&vgp[(size_t)(flat >> 5) * SEQ + j0 + (flat & 31)];
  }
}

// ---------------- Flash attention: QT=64 (4 waves x 16 rows), KT=32 --------
__global__ __launch_bounds__(256) void attn_kernel(const bf16* __restrict__ q, const bf16* __restrict__ k,
                                                   const bf16* __restrict__ vt, bf16* __restrict__ ao) {
  __shared__ bf16 smem[21248];
  bf16* const qs  = smem;
  bf16* const ksl = smem;
  bf16* const vtl = smem + 8448;
  bf16* const pl  = smem + 18688;
  int qt = blockIdx.x;
  const int h = blockIdx.y, b = blockIdx.z;
  if (b) qt = 31 - qt;
  const int kvh = h >> 1;
  const int t = threadIdx.x, lane = t & 63, w = t >> 6;
  const int r16 = lane & 15, g = lane >> 4;
  const int i_base = qt * 64;

  {
    const bf16* qg = q + ((size_t)(b * SEQ + i_base)) * NQ + h * 256;
#pragma unroll
    for (int it = 0; it < 8; ++it) {
      const int flat = it * 2048 + t * 8;
      const int row = flat >> 8, dd = flat & 255;
      *(bf16x8*)&qs[row * 264 + dd] = *(const bf16x8*)&qg[(size_t)row * NQ + dd];
    }
  }
  __syncthreads();
  bf16x8 aq[8];
#pragma unroll
  for (int c = 0; c < 8; ++c) aq[c] = *(const bf16x8*)&qs[(w * 16 + r16) * 264 + c * 32 + g * 8];

  f32x4 oacc[16] = {};
  float lrun[4] = {0.f, 0.f, 0.f, 0.f};
  int jb = i_base - 1023; if (jb < 0) jb = 0; jb &= ~31;
  const int je = i_base + 63;
  const bf16* kg = k + (size_t)b * SEQ * NKV + kvh * 256;
  const bf16* vg = vt + ((size_t)b * NKV + kvh * 256) * SEQ;

  bf16x8 kr[4], vr[4];
  attn_load(kg, vg, jb, t, kr, vr);

  for (int j0 = jb; j0 <= je; j0 += 32) {
    __syncthreads();
#pragma unroll
    for (int it = 0; it < 4; ++it) {
      const int flat = it * 2048 + t * 8;
      *(bf16x8*)&ksl[(flat >> 8) * 264 + (flat & 255)] = kr[it];
      *(bf16x8*)&vtl[(flat >> 5) * 40 + (flat & 31)] = vr[it];
    }
    __syncthreads();
    const int jn = (j0 + 32 <= je) ? (j0 + 32) : j0;
    attn_load(kg, vg, jn, t, kr, vr);

    f32x4 sc0 = {}, sc1 = {};
#pragma unroll
    for (int c = 0; c < 8; ++c) {
      const bf16x8 b0 = *(const bf16x8*)&ksl[r16 * 264 + c * 32 + g * 8];
      const bf16x8 b1 = *(const bf16x8*)&ksl[(16 + r16) * 264 + c * 32 + g * 8];
      sc0 = __builtin_amdgcn_mfma_f32_16x16x32_bf16(aq[c], b0, sc0, 0, 0, 0);
      sc1 = __builtin_amdgcn_mfma_f32_16x16x32_bf16(aq[c], b1, sc1, 0, 0, 0);
    }
    const bool full = (j0 + 31 <= i_base) && (i_base + 63 - j0 < 1024);
#pragma unroll
    for (int e = 0; e < 4; ++e) {
      const float t0 = __expf(sc0[e] * 0.0025f);
      const float t1 = __expf(sc1[e] * 0.0025f);
      float p0 = __expf(-100.0f / (t0 + 1.0f));
      float p1 = __expf(-100.0f / (t1 + 1.0f));
      if (!full) {
        const int irow = i_base + w * 16 + g * 4 + e;
        const int jg0 = j0 + r16, jg1 = j0 + 16 + r16;
        if (jg0 > irow || irow - jg0 >= 1024) p0 = 0.f;
        if (jg1 > irow || irow - jg1 >= 1024) p1 = 0.f;
      }
      const bf16 b0 = (bf16)p0, b1 = (bf16)p1;
      lrun[e] += (float)b0 + (float)b1;
      pl[w * 640 + (g * 4 + e) * 40 + r16] = b0;
      pl[w * 640 + (g * 4 + e) * 40 + 16 + r16] = b1;
    }
    const bf16x8 pa = *(const bf16x8*)&pl[w * 640 + r16 * 40 + g * 8];
#pragma unroll
    for (int nf = 0; nf < 16; ++nf) {
      const bf16x8 vb = *(const bf16x8*)&vtl[(nf * 16 + r16) * 40 + g * 8];
      oacc[nf] = __builtin_amdgcn_mfma_f32_16x16x32_bf16(pa, vb, oacc[nf], 0, 0, 0);
    }
  }
  float inv[4];
#pragma unroll
  for (int e = 0; e < 4; ++e) {
#pragma unroll
    for (int o = 1; o < 16; o <<= 1) lrun[e] += __shfl_xor(lrun[e], o, 64);
    inv[e] = 1.0f / lrun[e];
  }
  bf16* aor = ao + ((size_t)(b * SEQ + i_base + w * 16)) * NQ + h * 256;
#pragma unroll
  for (int nf = 0; nf < 16; ++nf)
#pragma unroll
    for (int e = 0; e < 4; ++e)
      aor[(size_t)(g * 4 + e) * NQ + nf * 16 + r16] = (bf16)(oacc[nf][e] * inv[e]);
}

extern "C" void kernel_launch(void* const* d_in, const int* in_sizes, int n_in,
                              void* d_out, int out_size, void* d_ws, size_t ws_size,
                              hipStream_t stream) {
  const float* hs   = (const float*)d_in[0];
  const float* cosb = (const float*)d_in[1];
  const float* sinb = (const float*)d_in[2];
  const float* rw   = (const float*)d_in[3];
  const float* Wq   = (const float*)d_in[4];
  const float* Wk   = (const float*)d_in[5];
  const float* Wv   = (const float*)d_in[6];
  const float* Wo   = (const float*)d_in[7];
  float* out = (float*)d_out;
  char* ws = (char*)d_ws;

  bf16* xb   = (bf16*)(ws);             // 4096x2304
  bf16* wqkv = (bf16*)(ws + 18874368);  // [4096][2304]: Wq(2048) | Wk(1024) | Wv(1024)
  bf16* wkb  = wqkv + (size_t)2048 * 2304;
  bf16* wvb  = wqkv + (size_t)3072 * 2304;
  bf16* wob  = (bf16*)(ws + 37748736);  // 2304x2048
  bf16* qg   = (bf16*)(ws + 47185920);  // 4096x2048
  bf16* kg   = (bf16*)(ws + 63963136);  // 4096x1024
  bf16* vtg  = (bf16*)(ws + 72351744);  // [2][1024][2048]
  bf16* ag   = (bf16*)(ws + 80740352);  // 4096x2048

  rmsnorm_kernel<<<4096, 256, 0, stream>>>(hs, rw, xb);
  cvt4_kernel<<<(NW0 + 2 * NW1 + NW3) / 4 / 256, 256, 0, stream>>>(Wq, Wk, Wv, Wo, wqkv, wkb, wvb, wob);
  // QKV: M=4096, N=4096, K=2304 (NT=36), grid 16x16=256
  gemm8p<36, 16, 0><<<256, 512, 0, stream>>>(xb, wqkv, qg, kg, vtg, nullptr, nullptr, 4096);
  rope_kernel<<<(4096 * 8 * 128 + 4096 * 4 * 128) / 256, 256, 0, stream>>>(qg, kg, cosb, sinb);
  attn_kernel<<<dim3(32, 8, 2), 256, 0, stream>>>(qg, kg, vtg, ag);
  // O-proj: M=4096, N=2304, K=2048 (NT=32), grid 16x9=144, +residual
  gemm8p<32, 9, 1><<<144, 512, 0, stream>>>(ag, wob, nullptr, nullptr, nullptr, out, hs, 2304);
}

// Round 5
// 266.689 us; speedup vs baseline: 1.3327x; 1.0037x over previous
//
#include <hip/hip_runtime.h>
#include <cstdint>

typedef __bf16 bf16;
typedef __bf16 bf16x8 __attribute__((ext_vector_type(8)));
typedef __bf16 bf16x4 __attribute__((ext_vector_type(4)));
typedef float  f32x4  __attribute__((ext_vector_type(4)));

#define HIDDEN 2304
#define NQ 2048
#define NKV 1024
#define SEQ 2048

typedef __attribute__((address_space(1))) void gv_t;
typedef __attribute__((address_space(3))) void lv_t;
__device__ __forceinline__ void gld16(const void* g, void* l) {
  __builtin_amdgcn_global_load_lds((gv_t*)g, (lv_t*)l, 16, 0, 0);
}

#define BAR()    asm volatile("s_barrier" ::: "memory")
#define LGKM0()  asm volatile("s_waitcnt lgkmcnt(0)" ::: "memory")
#define VM6()    asm volatile("s_waitcnt vmcnt(6)" ::: "memory")
#define VM0()    asm volatile("s_waitcnt vmcnt(0)" ::: "memory")
#define SCHED0() __builtin_amdgcn_sched_barrier(0)

// ---------------- RMSNorm + bf16 cast ----------------
__global__ __launch_bounds__(256) void rmsnorm_kernel(const float* __restrict__ x,
                                                      const float* __restrict__ w,
                                                      bf16* __restrict__ xb) {
  const int row = blockIdx.x, t = threadIdx.x;
  const float* xr = x + (size_t)row * HIDDEN;
  float v[9]; float ss = 0.f;
#pragma unroll
  for (int i = 0; i < 9; ++i) { v[i] = xr[t + i * 256]; ss += v[i] * v[i]; }
#pragma unroll
  for (int o = 32; o; o >>= 1) ss += __shfl_xor(ss, o, 64);
  __shared__ float wss[4];
  if ((t & 63) == 0) wss[t >> 6] = ss;
  __syncthreads();
  ss = wss[0] + wss[1] + wss[2] + wss[3];
  const float rs = rsqrtf(ss * (1.0f / HIDDEN) + 1e-6f);
  bf16* xo = xb + (size_t)row * HIDDEN;
#pragma unroll
  for (int i = 0; i < 9; ++i) xo[t + i * 256] = (bf16)(v[i] * rs * (1.0f + w[t + i * 256]));
}

// ---------------- fused f32 -> bf16 weight convert (Wq,Wk,Wv,Wo) ----------
#define NW0 (2048 * 2304)
#define NW1 (1024 * 2304)
#define NW3 (2304 * 2048)
__global__ __launch_bounds__(256) void cvt4_kernel(const float* __restrict__ s0, const float* __restrict__ s1,
                                                   const float* __restrict__ s2, const float* __restrict__ s3,
                                                   bf16* __restrict__ d0, bf16* __restrict__ d1,
                                                   bf16* __restrict__ d2, bf16* __restrict__ d3) {
  int i = (blockIdx.x * 256 + threadIdx.x) * 4;
  const float* s; bf16* d;
  if (i < NW0) { s = s0; d = d0; }
  else if (i < NW0 + NW1) { s = s1; d = d1; i -= NW0; }
  else if (i < NW0 + 2 * NW1) { s = s2; d = d2; i -= NW0 + NW1; }
  else { s = s3; d = d3; i -= NW0 + 2 * NW1; }
  const float4 f = *(const float4*)(s + i);
  bf16x4 o; o.x = (bf16)f.x; o.y = (bf16)f.y; o.z = (bf16)f.z; o.w = (bf16)f.w;
  *(bf16x4*)(d + i) = o;
}

// ---------------- RoPE in-place on q and k (bf16) ----------------
__global__ __launch_bounds__(256) void rope_kernel(bf16* __restrict__ q, bf16* __restrict__ k,
                                                   const float* __restrict__ cosb,
                                                   const float* __restrict__ sinb) {
  const int tid = blockIdx.x * 256 + threadIdx.x;
  const int QN = 4096 * 8 * 128;
  const int KN = 4096 * 4 * 128;
  bf16* p; int row, d;
  if (tid < QN) {
    row = tid >> 10; const int rem = tid & 1023; d = rem & 127;
    p = q + (size_t)row * NQ + (rem >> 7) * 256 + d;
  } else {
    const int t2 = tid - QN; if (t2 >= KN) return;
    row = t2 >> 9; const int rem = t2 & 511; d = rem & 127;
    p = k + (size_t)row * NKV + (rem >> 7) * 256 + d;
  }
  const size_t cb = (size_t)row * 256 + d;
  const float c0 = cosb[cb], s0 = sinb[cb], c1 = cosb[cb + 128], s1 = sinb[cb + 128];
  const float a = (float)p[0], b = (float)p[128];
  p[0]   = (bf16)(a * c0 - b * s0);
  p[128] = (bf16)(b * c1 + a * s1);
}

// ======== 256x256 8-phase GEMM (T1+T2+T3+T4+T5), C = A[M,K]*B[N,K]^T ========
// 512 threads = 8 waves (2M x 4N). BK=64. LDS: 2 x 64KB buffers, each
// {A0,A1,B0,B1} 16KB halves ([128 rows][128 bytes], T2 XOR-swizzled via
// pre-swizzled GLOBAL source + XOR on ds_read addr; LDS dest linear).
// Schedule is PINNED with sched_barrier(0) (rule #18: MFMAs are register-only
// and otherwise drift across inline-asm barriers).
// Region-overwrite safety: each phase ends {BAR after LGKM0} so by the end of
// phase p every wave's ds_reads issued up to p are COMPLETE. A0(t+2) staged in
// P3 (a0 readers fenced end-P2); A1(t+2)/B0(t+2) staged in P4 (a1 fenced
// end-P3, bb fenced end-P2); B1(t+1) staged in P1 into opposite-parity buffer.
// vmcnt(6) once per tile at P4 confirms all 4 halves of tile t+1.
__device__ __forceinline__ void stage_half(const char* gbase, int stride, char* ldshalf, int tid) {
  const int c2 = ((tid & 7) * 16) ^ (((tid >> 3) & 7) << 4);  // pre-swizzled global col
#pragma unroll
  for (int q = 0; q < 2; ++q) {
    const int r = q * 64 + (tid >> 3);
    gld16(gbase + (size_t)r * stride + c2, ldshalf + q * 8192 + tid * 16);
  }
}

template<int MH, int NH>
__device__ __forceinline__ void mfma_cluster(const bf16x8 (&af)[4][2], const bf16x8 (&bn)[2][2],
                                             f32x4 (&acc)[8][4]) {
  __builtin_amdgcn_s_setprio(1);
#pragma unroll
  for (int m = 0; m < 4; ++m)
#pragma unroll
    for (int n = 0; n < 2; ++n) {
      f32x4 c = acc[MH * 4 + m][NH * 2 + n];
      c = __builtin_amdgcn_mfma_f32_16x16x32_bf16(af[m][0], bn[n][0], c, 0, 0, 0);
      c = __builtin_amdgcn_mfma_f32_16x16x32_bf16(af[m][1], bn[n][1], c, 0, 0, 0);
      acc[MH * 4 + m][NH * 2 + n] = c;
    }
  __builtin_amdgcn_s_setprio(0);
}

// MODE 0: fused QKV epilogue (N=4096: Q | K | V^T regions, 256-aligned).
// MODE 1: f32 out = acc + residual (direct store).
template<int NT, int NY, int MODE>
__global__ __launch_bounds__(512) void gemm8p(const bf16* __restrict__ A, const bf16* __restrict__ B,
                                              bf16* __restrict__ Cq, bf16* __restrict__ Ck,
                                              bf16* __restrict__ Cvt, float* __restrict__ fo,
                                              const float* __restrict__ resid, int Nd) {
  __shared__ char lds[131072];
  const int Ks = NT * 128;  // row stride in BYTES
  const char* Aby = (const char*)A;
  const char* Bby = (const char*)B;

  int wg = blockIdx.x;
  const int chunk = (int)gridDim.x >> 3;          // grids are multiples of 8
  wg = (wg & 7) * chunk + (wg >> 3);              // XCD-bijective swizzle
  const int by = wg % NY, bx = wg / NY;
  const int m0 = bx * 256, n0 = by * 256;

  const int tid = threadIdx.x, lane = tid & 63, wv = tid >> 6;
  const int wm = wv >> 2, wn = wv & 3;
  const int r16 = lane & 15, g = lane >> 4;
  const int xr = (r16 & 7) << 4;
  const int cb0 = (g * 16) ^ xr, cb1 = (64 + g * 16) ^ xr;
  const int rdA = wm * 16384 + r16 * 128;
  const int rdB = 32768 + (wn >> 1) * 16384 + (wn & 1) * 8192 + r16 * 128;

  f32x4 acc[8][4] = {};

  // ---- prologue: tile0 {A0,A1,B0,B1} -> buf0, tile1 {A0,A1,B0} -> buf1 ----
  stage_half(Aby + (size_t)m0 * Ks,           Ks, lds + 0,     tid);
  stage_half(Aby + (size_t)(m0 + 128) * Ks,   Ks, lds + 16384, tid);
  stage_half(Bby + (size_t)n0 * Ks,           Ks, lds + 32768, tid);
  stage_half(Bby + (size_t)(n0 + 128) * Ks,   Ks, lds + 49152, tid);
  stage_half(Aby + (size_t)m0 * Ks + 128,         Ks, lds + 65536 + 0,     tid);
  stage_half(Aby + (size_t)(m0 + 128) * Ks + 128, Ks, lds + 65536 + 16384, tid);
  stage_half(Bby + (size_t)n0 * Ks + 128,         Ks, lds + 65536 + 32768, tid);
  VM6(); BAR();

  for (int t = 0; t < NT; ++t) {
    const char* bufc = lds + (size_t)(t & 1) * 65536;
    char* bufn = lds + (size_t)((t + 1) & 1) * 65536;
    char* bufs = lds + (size_t)(t & 1) * 65536;  // tile t+2 shares parity with t
    bf16x8 a0[4][2], a1[4][2], bb01[2][2], bb23[2][2];
    // ---- P1: read a0(8) + bb01(4); stage (t+1).B1 ----
#pragma unroll
    for (int m = 0; m < 4; ++m) {
      a0[m][0] = *(const bf16x8*)(bufc + rdA + m * 2048 + cb0);
      a0[m][1] = *(const bf16x8*)(bufc + rdA + m * 2048 + cb1);
    }
#pragma unroll
    for (int n = 0; n < 2; ++n) {
      bb01[n][0] = *(const bf16x8*)(bufc + rdB + n * 2048 + cb0);
      bb01[n][1] = *(const bf16x8*)(bufc + rdB + n * 2048 + cb1);
    }
    if (t + 1 < NT)
      stage_half(Bby + (size_t)(n0 + 128) * Ks + (size_t)(t + 1) * 128, Ks, bufn + 49152, tid);
    BAR(); LGKM0(); SCHED0();
    mfma_cluster<0, 0>(a0, bb01, acc);
    SCHED0(); BAR();
    // ---- P2: read bb23(4) ----
#pragma unroll
    for (int n = 0; n < 2; ++n) {
      bb23[n][0] = *(const bf16x8*)(bufc + rdB + (2 + n) * 2048 + cb0);
      bb23[n][1] = *(const bf16x8*)(bufc + rdB + (2 + n) * 2048 + cb1);
    }
    BAR(); LGKM0(); SCHED0();
    mfma_cluster<0, 1>(a0, bb23, acc);
    SCHED0(); BAR();
    // ---- P3: stage (t+2).A0 (a0 readers fenced end-P2); read a1(8) ----
    if (t + 2 < NT)
      stage_half(Aby + (size_t)m0 * Ks + (size_t)(t + 2) * 128, Ks, bufs + 0, tid);
#pragma unroll
    for (int m = 0; m < 4; ++m) {
      a1[m][0] = *(const bf16x8*)(bufc + rdA + 8192 + m * 2048 + cb0);
      a1[m][1] = *(const bf16x8*)(bufc + rdA + 8192 + m * 2048 + cb1);
    }
    BAR(); LGKM0(); SCHED0();
    mfma_cluster<1, 0>(a1, bb01, acc);
    SCHED0(); BAR();
    // ---- P4: stage (t+2).A1,B0; counted vmcnt confirms tile t+1 ----
    if (t + 2 < NT) {
      stage_half(Aby + (size_t)(m0 + 128) * Ks + (size_t)(t + 2) * 128, Ks, bufs + 16384, tid);
      stage_half(Bby + (size_t)n0 * Ks + (size_t)(t + 2) * 128, Ks, bufs + 32768, tid);
    }
    if (t < NT - 2) { VM6(); } else if (t == NT - 2) { VM0(); }
    BAR(); SCHED0();
    mfma_cluster<1, 1>(a1, bb23, acc);
    SCHED0(); BAR();
  }

  // ---- epilogue ----
  const int mrow = m0 + wm * 128 + g * 4;
  const int ncol = n0 + wn * 64 + r16;
#pragma unroll
  for (int i = 0; i < 8; ++i)
#pragma unroll
    for (int j = 0; j < 4; ++j)
#pragma unroll
      for (int e = 0; e < 4; ++e) {
        const int m = mrow + i * 16 + e;
        const int n = ncol + j * 16;
        const float vv = acc[i][j][e];
        if constexpr (MODE == 0) {
          if (n0 < 2048) {
            Cq[(size_t)m * 2048 + n] = (bf16)vv;
          } else if (n0 < 3072) {
            Ck[(size_t)m * 1024 + (n - 2048)] = (bf16)vv;
          } else {
            const int b2 = m >> 11, s = m & 2047;
            Cvt[((size_t)b2 * 1024 + (n - 3072)) * SEQ + s] = (bf16)vv;
          }
        } else {
          fo[(size_t)m * Nd + n] = vv + resid[(size_t)m * Nd + n];
        }
      }
}

// ---------------- attention tile loads (K 32x256, V^T 256x32) ----------------
__device__ __forceinline__ void attn_load(const bf16* __restrict__ kgp, const bf16* __restrict__ vgp,
                                          int j0, int t, bf16x8* kr, bf16x8* vr) {
#pragma unroll
  for (int it = 0; it < 4; ++it) {
    const int flat = it * 2048 + t * 8;
    kr[it] = *(const bf16x8*)&kgp[(size_t)((flat >> 8) + j0) * NKV + (flat & 255)];
    vr[it] = *(const bf16x8*)&vgp[(size_t)(flat >> 5) * SEQ + j0 + (flat & 31)];
  }
}

// ---------------- Flash attention: QT=64 (4 waves x 16 rows), KT=32 --------
__global__ __launch_bounds__(256) void attn_kernel(const bf16* __restrict__ q, const bf16* __restrict__ k,
                                                   const bf16* __restrict__ vt, bf16* __restrict__ ao) {
  __shared__ bf16 smem[21248];
  bf16* const qs  = smem;
  bf16* const ksl = smem;
  bf16* const vtl = smem + 8448;
  bf16* const pl  = smem + 18688;
  int qt = blockIdx.x;
  const int h = blockIdx.y, b = blockIdx.z;
  if (b) qt = 31 - qt;
  const int kvh = h >> 1;
  const int t = threadIdx.x, lane = t & 63, w = t >> 6;
  const int r16 = lane & 15, g = lane >> 4;
  const int i_base = qt * 64;

  {
    const bf16* qg = q + ((size_t)(b * SEQ + i_base)) * NQ + h * 256;
#pragma unroll
    for (int it = 0; it < 8; ++it) {
      const int flat = it * 2048 + t * 8;
      const int row = flat >> 8, dd = flat & 255;
      *(bf16x8*)&qs[row * 264 + dd] = *(const bf16x8*)&qg[(size_t)row * NQ + dd];
    }
  }
  __syncthreads();
  bf16x8 aq[8];
#pragma unroll
  for (int c = 0; c < 8; ++c) aq[c] = *(const bf16x8*)&qs[(w * 16 + r16) * 264 + c * 32 + g * 8];

  f32x4 oacc[16] = {};
  float lrun[4] = {0.f, 0.f, 0.f, 0.f};
  int jb = i_base - 1023; if (jb < 0) jb = 0; jb &= ~31;
  const int je = i_base + 63;
  const bf16* kg = k + (size_t)b * SEQ * NKV + kvh * 256;
  const bf16* vg = vt + ((size_t)b * NKV + kvh * 256) * SEQ;

  bf16x8 kr[4], vr[4];
  attn_load(kg, vg, jb, t, kr, vr);

  for (int j0 = jb; j0 <= je; j0 += 32) {
    __syncthreads();
#pragma unroll
    for (int it = 0; it < 4; ++it) {
      const int flat = it * 2048 + t * 8;
      *(bf16x8*)&ksl[(flat >> 8) * 264 + (flat & 255)] = kr[it];
      *(bf16x8*)&vtl[(flat >> 5) * 40 + (flat & 31)] = vr[it];
    }
    __syncthreads();
    const int jn = (j0 + 32 <= je) ? (j0 + 32) : j0;
    attn_load(kg, vg, jn, t, kr, vr);

    f32x4 sc0 = {}, sc1 = {};
#pragma unroll
    for (int c = 0; c < 8; ++c) {
      const bf16x8 b0 = *(const bf16x8*)&ksl[r16 * 264 + c * 32 + g * 8];
      const bf16x8 b1 = *(const bf16x8*)&ksl[(16 + r16) * 264 + c * 32 + g * 8];
      sc0 = __builtin_amdgcn_mfma_f32_16x16x32_bf16(aq[c], b0, sc0, 0, 0, 0);
      sc1 = __builtin_amdgcn_mfma_f32_16x16x32_bf16(aq[c], b1, sc1, 0, 0, 0);
    }
    const bool full = (j0 + 31 <= i_base) && (i_base + 63 - j0 < 1024);
#pragma unroll
    for (int e = 0; e < 4; ++e) {
      const float t0 = __expf(sc0[e] * 0.0025f);
      const float t1 = __expf(sc1[e] * 0.0025f);
      float p0 = __expf(-100.0f / (t0 + 1.0f));
      float p1 = __expf(-100.0f / (t1 + 1.0f));
      if (!full) {
        const int irow = i_base + w * 16 + g * 4 + e;
        const int jg0 = j0 + r16, jg1 = j0 + 16 + r16;
        if (jg0 > irow || irow - jg0 >= 1024) p0 = 0.f;
        if (jg1 > irow || irow - jg1 >= 1024) p1 = 0.f;
      }
      const bf16 b0 = (bf16)p0, b1 = (bf16)p1;
      lrun[e] += (float)b0 + (float)b1;
      pl[w * 640 + (g * 4 + e) * 40 + r16] = b0;
      pl[w * 640 + (g * 4 + e) * 40 + 16 + r16] = b1;
    }
    const bf16x8 pa = *(const bf16x8*)&pl[w * 640 + r16 * 40 + g * 8];
#pragma unroll
    for (int nf = 0; nf < 16; ++nf) {
      const bf16x8 vb = *(const bf16x8*)&vtl[(nf * 16 + r16) * 40 + g * 8];
      oacc[nf] = __builtin_amdgcn_mfma_f32_16x16x32_bf16(pa, vb, oacc[nf], 0, 0, 0);
    }
  }
  float inv[4];
#pragma unroll
  for (int e = 0; e < 4; ++e) {
#pragma unroll
    for (int o = 1; o < 16; o <<= 1) lrun[e] += __shfl_xor(lrun[e], o, 64);
    inv[e] = 1.0f / lrun[e];
  }
  bf16* aor = ao + ((size_t)(b * SEQ + i_base + w * 16)) * NQ + h * 256;
#pragma unroll
  for (int nf = 0; nf < 16; ++nf)
#pragma unroll
    for (int e = 0; e < 4; ++e)
      aor[(size_t)(g * 4 + e) * NQ + nf * 16 + r16] = (bf16)(oacc[nf][e] * inv[e]);
}

extern "C" void kernel_launch(void* const* d_in, const int* in_sizes, int n_in,
                              void* d_out, int out_size, void* d_ws, size_t ws_size,
                              hipStream_t stream) {
  const float* hs   = (const float*)d_in[0];
  const float* cosb = (const float*)d_in[1];
  const float* sinb = (const float*)d_in[2];
  const float* rw   = (const float*)d_in[3];
  const float* Wq   = (const float*)d_in[4];
  const float* Wk   = (const float*)d_in[5];
  const float* Wv   = (const float*)d_in[6];
  const float* Wo   = (const float*)d_in[7];
  float* out = (float*)d_out;
  char* ws = (char*)d_ws;

  bf16* xb   = (bf16*)(ws);             // 4096x2304
  bf16* wqkv = (bf16*)(ws + 18874368);  // [4096][2304]: Wq(2048) | Wk(1024) | Wv(1024)
  bf16* wkb  = wqkv + (size_t)2048 * 2304;
  bf16* wvb  = wqkv + (size_t)3072 * 2304;
  bf16* wob  = (bf16*)(ws + 37748736);  // 2304x2048
  bf16* qg   = (bf16*)(ws + 47185920);  // 4096x2048
  bf16* kg   = (bf16*)(ws + 63963136);  // 4096x1024
  bf16* vtg  = (bf16*)(ws + 72351744);  // [2][1024][2048]
  bf16* ag   = (bf16*)(ws + 80740352);  // 4096x2048

  rmsnorm_kernel<<<4096, 256, 0, stream>>>(hs, rw, xb);
  cvt4_kernel<<<(NW0 + 2 * NW1 + NW3) / 4 / 256, 256, 0, stream>>>(Wq, Wk, Wv, Wo, wqkv, wkb, wvb, wob);
  // QKV: M=4096, N=4096, K=2304 (NT=36), grid 16x16=256
  gemm8p<36, 16, 0><<<256, 512, 0, stream>>>(xb, wqkv, qg, kg, vtg, nullptr, nullptr, 4096);
  rope_kernel<<<(4096 * 8 * 128 + 4096 * 4 * 128) / 256, 256, 0, stream>>>(qg, kg, cosb, sinb);
  attn_kernel<<<dim3(32, 8, 2), 256, 0, stream>>>(qg, kg, vtg, ag);
  // O-proj: M=4096, N=2304, K=2048 (NT=32), grid 16x9=144, +residual
  gemm8p<32, 9, 1><<<144, 512, 0, stream>>>(ag, wob, nullptr, nullptr, nullptr, out, hs, 2304);
}